// Round 6
// baseline (369.537 us; speedup 1.0000x reference)
//
#include <hip/hip_runtime.h>
#include <math.h>

#define NEGV -9000000000000000.0f
#define WPB 16  // waves per block
#define NTHR 1024

// Packed W in LDS: WL[r][k][e] (float4) = W[r][e][4k..4k+3].
// Lane e reads WL[(r*16+k)*64+e]: 64 lanes stride 16B contiguous ->
// conflict-free ds_read_b128.
struct LdsW {
  float4 w[8 * 16 * 64];  // 128 KB
};

__device__ __forceinline__ float wave_sum(float v) {
#pragma unroll
  for (int m = 32; m; m >>= 1) v += __shfl_xor(v, m, 64);
  return v;
}

__device__ __forceinline__ void stage_W(float4* wl, const float* __restrict__ W) {
  const float4* Wg = (const float4*)W;
  for (int f = threadIdx.x; f < 8192; f += NTHR) {
    float4 v = Wg[f];  // coalesced global
    int r = f >> 10, e = (f >> 4) & 63, k = f & 15;
    wl[(((r << 4) + k) << 6) + e] = v;
  }
  __syncthreads();
}

// y_e = tanh(sum_d W[r][e=lane][d] * x[d]). W rows from LDS (per-lane,
// conflict-free), x via wave-uniform address (scalarizes to s_load /
// broadcast VMEM). fmaf chain order identical to all prior rounds.
__device__ __forceinline__ float transform_u(int nb, int r, int lane,
                                             const float* __restrict__ emb,
                                             const float4* wl) {
  const float4* wr = wl + (r << 10) + lane;
  const float4* xp = (const float4*)(emb + ((size_t)nb << 6));
  float acc = 0.f;
#pragma unroll
  for (int k = 0; k < 16; ++k) {
    float4 w = wr[k << 6];
    float4 x = xp[k];
    acc = fmaf(w.x, x.x, acc);
    acc = fmaf(w.y, x.y, acc);
    acc = fmaf(w.z, x.z, acc);
    acc = fmaf(w.w, x.w, acc);
  }
  return tanhf(acc);
}

// Score 64 neighbors of eid (neighbors grouped by relation, W of the current
// relation cached in VGPRs; x via uniform loads), masked softmax, top-8
// (value desc, index asc), second masked softmax. All numerics bit-identical
// to prior rounds. Outputs: per-lane nbr/rel, selected indices, weights.
__device__ __forceinline__ void score_select(int eid, int b, int lane,
                                             const float* __restrict__ emb,
                                             const float4* wl,
                                             const int* __restrict__ adjE,
                                             const int* __restrict__ adjR,
                                             const float* __restrict__ user_emb,
                                             int& nbr, int& rel, int seli[8],
                                             float wout[8]) {
  nbr = adjE[((size_t)eid << 6) + lane];
  rel = adjR[((size_t)eid << 6) + lane];
  float u_e = user_emb[((size_t)b << 6) + lane];
  // rank of this lane in relation-sorted order (stable within relation)
  int myrank = 0, basec = 0;
  int cnt[8];
  unsigned long long ltmask = (1ull << lane) - 1ull;
#pragma unroll
  for (int rr = 0; rr < 8; ++rr) {
    unsigned long long m = __ballot(rel == rr);
    if (rel == rr) myrank = basec + (int)__popcll(m & ltmask);
    cnt[rr] = (int)__popcll(m);
    basec += cnt[rr];
  }
  // order[k] = original neighbor index of k-th sorted element (push-permute)
  int order = __builtin_amdgcn_ds_permute(myrank << 2, lane);
  int srt_nb = __shfl(nbr, order, 64);  // neighbor entity of k-th sorted
  float s_mine = 0.f;
  int pos = 0;
#pragma unroll
  for (int rr = 0; rr < 8; ++rr) {
    int c = cnt[rr];
    if (c == 0) continue;
    // cache W[rr] row of this lane in VGPRs, reused across the group
    const float4* wr = wl + (rr << 10) + lane;
    float4 wv[16];
#pragma unroll
    for (int k = 0; k < 16; ++k) wv[k] = wr[k << 6];
    for (int q = 0; q < c; ++q, ++pos) {
      int n = __builtin_amdgcn_readlane(order, pos);    // SGPR broadcast
      int nb = __builtin_amdgcn_readlane(srt_nb, pos);  // SGPR broadcast
      const float4* xp = (const float4*)(emb + ((size_t)nb << 6));
      float acc = 0.f;
#pragma unroll
      for (int k = 0; k < 16; ++k) {
        float4 x = xp[k];  // uniform address -> scalar load
        acc = fmaf(wv[k].x, x.x, acc);
        acc = fmaf(wv[k].y, x.y, acc);
        acc = fmaf(wv[k].z, x.z, acc);
        acc = fmaf(wv[k].w, x.w, acc);
      }
      float y = tanhf(acc);
      float totv = wave_sum(u_e * y);
      if (lane == n) s_mine = totv * (1.0f / 64.0f);
    }
  }
  // ---- masked softmax over 64 neighbors (bit-exact) ----
  float sv = (s_mine == 0.0f) ? NEGV : s_mine;
  float mx = sv;
#pragma unroll
  for (int m = 32; m; m >>= 1) mx = fmaxf(mx, __shfl_xor(mx, m, 64));
  float p = expf(sv - mx);
  float Z = wave_sum(p);
  p /= Z;
  // top-8: iterative butterfly argmax with (value desc, index asc)
  float v = p;
  int vi = lane;
  float selv[8];
#pragma unroll
  for (int j = 0; j < 8; ++j) {
    float bv = v;
    int bi = vi;
#pragma unroll
    for (int m = 1; m < 64; m <<= 1) {
      float ov = __shfl_xor(bv, m, 64);
      int oi = __shfl_xor(bi, m, 64);
      if (ov > bv || (ov == bv && oi < bi)) { bv = ov; bi = oi; }
    }
    selv[j] = bv;
    seli[j] = bi;
    if (lane == bi) v = -__builtin_inff();
  }
  // second masked softmax over the 8 selected
  float m8 = -__builtin_inff();
#pragma unroll
  for (int j = 0; j < 8; ++j) {
    float tt = (selv[j] == 0.f) ? NEGV : selv[j];
    selv[j] = tt;
    m8 = fmaxf(m8, tt);
  }
  float Z8 = 0.f;
#pragma unroll
  for (int j = 0; j < 8; ++j) {
    selv[j] = expf(selv[j] - m8);
    Z8 += selv[j];
  }
#pragma unroll
  for (int j = 0; j < 8; ++j) wout[j] = selv[j] / Z8;
}

// ---- user embedding: 4 waves/block, wave = one batch element ----
__global__ __launch_bounds__(256) void k_user(const int* __restrict__ ui,
                                              const float* __restrict__ emb,
                                              const int* __restrict__ clicked,
                                              const float* __restrict__ numc, int hist,
                                              float* __restrict__ user_emb, int ntask) {
  int w = threadIdx.x >> 6, lane = threadIdx.x & 63;
  int b = blockIdx.x * 4 + w;
  if (b >= ntask) return;
  int u = ui[b];
  float acc = 0.f;
  for (int h = 0; h < hist; ++h) {
    int it = clicked[u * hist + h];
    acc += emb[((size_t)it << 6) + lane];
  }
  user_emb[((size_t)b << 6) + lane] = acc * (1.0f / numc[u]);
}

// ---- hop0: score + topsel + transform the 8 selected -> e1, s0w, emb1 ----
__global__ __launch_bounds__(NTHR, 4) void k_hop0_f(
    const int* __restrict__ ii, const float* __restrict__ emb,
    const float* __restrict__ W, const int* __restrict__ adjE,
    const int* __restrict__ adjR, const float* __restrict__ user_emb,
    int* __restrict__ e1, float* __restrict__ s0w, float* __restrict__ emb1,
    int ntask) {
  __shared__ LdsW S;
  stage_W(S.w, W);
  int w = threadIdx.x >> 6, lane = threadIdx.x & 63;
  int wid = blockIdx.x * WPB + w;
  int tot = gridDim.x * WPB;
  for (int t = wid; t < ntask; t += tot) {
    int eid = ii[t];
    int nbr, rel, seli[8];
    float w8[8];
    score_select(eid, t, lane, emb, S.w, adjE, adjR, user_emb, nbr, rel, seli, w8);
#pragma unroll
    for (int j = 0; j < 8; ++j) {
      int nb = __builtin_amdgcn_readfirstlane(__shfl(nbr, seli[j], 64));
      int rr = __builtin_amdgcn_readfirstlane(__shfl(rel, seli[j], 64));
      float y = transform_u(nb, rr, lane, emb, S.w);
      emb1[(((size_t)t * 8 + j) << 6) + lane] = y;
      if (lane == 0) {
        e1[t * 8 + j] = nb;
        s0w[t * 8 + j] = w8[j];
      }
    }
  }
}

// ---- hop1: score + topsel + fused aggregation (emb + labels) ----
__global__ __launch_bounds__(NTHR, 4) void k_hop1_f(
    const int* __restrict__ ui, const int* __restrict__ ii, const float* __restrict__ emb,
    const float* __restrict__ W, const int* __restrict__ adjE,
    const int* __restrict__ adjR, const float* __restrict__ labels, int np1,
    const float* __restrict__ user_emb, const int* __restrict__ e1,
    const float* __restrict__ emb1, float* __restrict__ emb1p,
    float* __restrict__ lab1p, int ntask) {
  __shared__ LdsW S;
  stage_W(S.w, W);
  int w = threadIdx.x >> 6, lane = threadIdx.x & 63;
  int wid = blockIdx.x * WPB + w;
  int tot = gridDim.x * WPB;
  for (int bj = wid; bj < ntask; bj += tot) {
    int b = bj >> 3;
    int u = ui[b];
    int item = ii[b];
    int eid = e1[bj];
    int nbr, rel, seli[8];
    float w8[8];
    score_select(eid, b, lane, emb, S.w, adjE, adjR, user_emb, nbr, rel, seli, w8);
    float agg = 0.f, labagg = 0.f;
#pragma unroll
    for (int k = 0; k < 8; ++k) {
      int nb = __builtin_amdgcn_readfirstlane(__shfl(nbr, seli[k], 64));
      int rr = __builtin_amdgcn_readfirstlane(__shfl(rel, seli[k], 64));
      float wk = w8[k];
      float y = transform_u(nb, rr, lane, emb, S.w);
      agg = fmaf(wk, y, agg);
      float raw2 = labels[(size_t)u * np1 + nb];
      float lab2 = (nb != item) ? raw2 : 0.5f;
      labagg = fmaf(wk, lab2, labagg);
    }
    float base = emb1[((size_t)bj << 6) + lane];
    emb1p[((size_t)bj << 6) + lane] = fmaxf(fmaf(agg, 0.125f, base), 0.f);
    if (lane == 0) {
      float raw1 = labels[(size_t)u * np1 + eid];
      bool hm = (eid != item);
      float l1 = hm ? raw1 : 0.5f;
      bool reset1 = (raw1 != 0.5f) && hm;
      lab1p[bj] = reset1 ? l1 : labagg;
    }
  }
}

__global__ __launch_bounds__(256) void k_final(const int* __restrict__ ii,
                                               const float* __restrict__ emb,
                                               const float* __restrict__ user_emb,
                                               const float* __restrict__ s0,
                                               const float* __restrict__ emb1,
                                               const float* __restrict__ emb1p,
                                               const float* __restrict__ lab1p,
                                               float* __restrict__ out, int bs) {
  int w = threadIdx.x >> 6, lane = threadIdx.x & 63;
  int b = blockIdx.x * 4 + w;
  if (b >= bs) return;
  int item = ii[b];
  float ue = user_emb[((size_t)b << 6) + lane];
  float agg = 0.f, aggp = 0.f, lab = 0.f;
#pragma unroll
  for (int j = 0; j < 8; ++j) {
    float s = s0[b * 8 + j];
    agg = fmaf(s, emb1[(((size_t)b * 8 + j) << 6) + lane], agg);
    aggp = fmaf(s, emb1p[(((size_t)b * 8 + j) << 6) + lane], aggp);
    lab = fmaf(s, lab1p[b * 8 + j], lab);
  }
  float e0 = emb[((size_t)item << 6) + lane];
  float h = fmaxf(fmaf(agg, 0.125f, e0), 0.f);  // relu(agg01 + emb0)
  float h2 = tanhf(fmaf(aggp, 0.125f, h));      // tanh(agg01' + emb0')
  float dot = wave_sum(ue * h2);
  if (lane == 0) {
    out[b] = 1.f / (1.f + expf(-dot));
    out[bs + b] = 1.f / (1.f + expf(-(lab - 0.5f)));
  }
}

extern "C" void kernel_launch(void* const* d_in, const int* in_sizes, int n_in, void* d_out,
                              int out_size, void* d_ws, size_t ws_size, hipStream_t stream) {
  const int* ui = (const int*)d_in[0];
  const int* ii = (const int*)d_in[1];
  const float* emb = (const float*)d_in[2];
  const float* W = (const float*)d_in[3];
  const int* adjE = (const int*)d_in[4];
  const int* adjR = (const int*)d_in[5];
  const int* clicked = (const int*)d_in[6];
  const float* numc = (const float*)d_in[7];
  const float* labels = (const float*)d_in[8];

  int bs = in_sizes[0];
  int np1 = in_sizes[2] / 64;  // n_entity + 1 (= labels row stride = offset)
  int nuser = in_sizes[7];
  int hist = in_sizes[6] / nuser;

  // workspace layout
  float* user_emb = (float*)d_ws;               // bs*64
  float* s0w = user_emb + (size_t)bs * 64;      // bs*8
  int* e1 = (int*)(s0w + (size_t)bs * 8);       // bs*8
  float* emb1 = (float*)(e1 + (size_t)bs * 8);  // bs*8*64
  float* emb1p = emb1 + (size_t)bs * 8 * 64;    // bs*8*64
  float* lab1p = emb1p + (size_t)bs * 8 * 64;   // bs*8

  int nt0 = bs;      // hop0 tasks
  int nt1 = bs * 8;  // hop1 tasks
  int nblk0 = (nt0 + WPB - 1) / WPB;  // 1 task per wave

  k_user<<<(nt0 + 3) / 4, 256, 0, stream>>>(ui, emb, clicked, numc, hist, user_emb, nt0);
  k_hop0_f<<<nblk0, NTHR, 0, stream>>>(ii, emb, W, adjE, adjR, user_emb, e1, s0w, emb1,
                                       nt0);
  k_hop1_f<<<256, NTHR, 0, stream>>>(ui, ii, emb, W, adjE, adjR, labels, np1, user_emb,
                                     e1, emb1, emb1p, lab1p, nt1);
  k_final<<<(nt0 + 3) / 4, 256, 0, stream>>>(ii, emb, user_emb, s0w, emb1, emb1p, lab1p,
                                             (float*)d_out, bs);
}

// Round 7
// 337.372 us; speedup vs baseline: 1.0953x; 1.0953x over previous
//
#include <hip/hip_runtime.h>
#include <math.h>

#define NEGV -9000000000000000.0f
#define WPB 16  // waves per block
#define NTHR 1024

// Packed W in LDS: WL[r][k][e] (float4) = W[r][e][4k..4k+3].
// Lane e reads WL[(r*16+k)*64+e]: 64 lanes stride 16B contiguous ->
// conflict-free ds_read_b128.
struct LdsW {
  float4 w[8 * 16 * 64];  // 128 KB
};

__device__ __forceinline__ float wave_sum(float v) {
#pragma unroll
  for (int m = 32; m; m >>= 1) v += __shfl_xor(v, m, 64);
  return v;
}

// Broadcast lane l's value of v to all lanes via v_readlane (VALU, no DS).
__device__ __forceinline__ float lane_bcast(float v, int l) {
  return __uint_as_float(__builtin_amdgcn_readlane(__float_as_uint(v), l));
}

__device__ __forceinline__ void stage_W(float4* wl, const float* __restrict__ W) {
  const float4* Wg = (const float4*)W;
  for (int f = threadIdx.x; f < 8192; f += NTHR) {
    float4 v = Wg[f];  // coalesced global
    int r = f >> 10, e = (f >> 4) & 63, k = f & 15;
    wl[(((r << 4) + k) << 6) + e] = v;
  }
  __syncthreads();
}

// y = tanh(sum_d W[r][lane][d] * x[d]) with x held lane-strided in xv and
// broadcast via readlane; W row from LDS. fmaf chain order (d ascending)
// identical to all prior rounds -> bit-exact.
__device__ __forceinline__ float transform_rl(int nb, int r, int lane,
                                              const float* __restrict__ emb,
                                              const float4* wl) {
  float xv = emb[((size_t)nb << 6) + lane];  // one lane-strided 256B load
  const float4* wr = wl + (r << 10) + lane;
  float acc = 0.f;
#pragma unroll
  for (int k = 0; k < 16; ++k) {
    float4 w = wr[k << 6];
    acc = fmaf(w.x, lane_bcast(xv, 4 * k + 0), acc);
    acc = fmaf(w.y, lane_bcast(xv, 4 * k + 1), acc);
    acc = fmaf(w.z, lane_bcast(xv, 4 * k + 2), acc);
    acc = fmaf(w.w, lane_bcast(xv, 4 * k + 3), acc);
  }
  return tanhf(acc);
}

// Score 64 neighbors of eid (grouped by relation; W of the current relation
// cached in (A)GPRs; x lane-strided + readlane broadcast, 1-ahead prefetch),
// masked softmax, top-8 (value desc, index asc), second masked softmax.
// All float ops bit-identical to prior rounds.
__device__ __forceinline__ void score_select(int eid, int b, int lane,
                                             const float* __restrict__ emb,
                                             const float4* wl,
                                             const int* __restrict__ adjE,
                                             const int* __restrict__ adjR,
                                             const float* __restrict__ user_emb,
                                             int& nbr, int& rel, int seli[8],
                                             float wout[8]) {
  nbr = adjE[((size_t)eid << 6) + lane];
  rel = adjR[((size_t)eid << 6) + lane];
  float u_e = user_emb[((size_t)b << 6) + lane];
  // rank of this lane in relation-sorted order (stable within relation)
  int myrank = 0, basec = 0;
  unsigned long long ltmask = (1ull << lane) - 1ull;
#pragma unroll
  for (int rr = 0; rr < 8; ++rr) {
    unsigned long long m = __ballot(rel == rr);
    if (rel == rr) myrank = basec + (int)__popcll(m & ltmask);
    basec += (int)__popcll(m);
  }
  // order[k] = original neighbor index of k-th sorted element (push-permute)
  int order = __builtin_amdgcn_ds_permute(myrank << 2, lane);
  int srt_nb = __shfl(nbr, order, 64);  // neighbor entity of k-th sorted
  int srt_r = __shfl(rel, order, 64);   // relation of k-th sorted

  int nb0 = __builtin_amdgcn_readlane(srt_nb, 0);
  float xv = emb[((size_t)nb0 << 6) + lane];  // prefetch first x
  float4 wv[16];
  int rcur = -1;
  float s_mine = 0.f;
  for (int pos = 0; pos < 64; ++pos) {
    int r = __builtin_amdgcn_readlane(srt_r, pos);
    if (r != rcur) {  // wave-uniform branch; ~8 reloads per task
      const float4* wr = wl + (r << 10) + lane;
#pragma unroll
      for (int k = 0; k < 16; ++k) wv[k] = wr[k << 6];
      rcur = r;
    }
    float xnext = 0.f;
    if (pos < 63) {  // issue next x load; latency hidden by this matvec
      int nbn = __builtin_amdgcn_readlane(srt_nb, pos + 1);
      xnext = emb[((size_t)nbn << 6) + lane];
    }
    float acc = 0.f;
#pragma unroll
    for (int k = 0; k < 16; ++k) {
      acc = fmaf(wv[k].x, lane_bcast(xv, 4 * k + 0), acc);
      acc = fmaf(wv[k].y, lane_bcast(xv, 4 * k + 1), acc);
      acc = fmaf(wv[k].z, lane_bcast(xv, 4 * k + 2), acc);
      acc = fmaf(wv[k].w, lane_bcast(xv, 4 * k + 3), acc);
    }
    float y = tanhf(acc);
    float totv = wave_sum(u_e * y);
    int n = __builtin_amdgcn_readlane(order, pos);
    if (lane == n) s_mine = totv * (1.0f / 64.0f);
    xv = xnext;
  }
  // ---- masked softmax over 64 neighbors (bit-exact) ----
  float sv = (s_mine == 0.0f) ? NEGV : s_mine;
  float mx = sv;
#pragma unroll
  for (int m = 32; m; m >>= 1) mx = fmaxf(mx, __shfl_xor(mx, m, 64));
  float p = expf(sv - mx);
  float Z = wave_sum(p);
  p /= Z;
  // top-8: iterative butterfly argmax with (value desc, index asc)
  float v = p;
  int vi = lane;
  float selv[8];
#pragma unroll
  for (int j = 0; j < 8; ++j) {
    float bv = v;
    int bi = vi;
#pragma unroll
    for (int m = 1; m < 64; m <<= 1) {
      float ov = __shfl_xor(bv, m, 64);
      int oi = __shfl_xor(bi, m, 64);
      if (ov > bv || (ov == bv && oi < bi)) { bv = ov; bi = oi; }
    }
    selv[j] = bv;
    seli[j] = bi;
    if (lane == bi) v = -__builtin_inff();
  }
  // second masked softmax over the 8 selected
  float m8 = -__builtin_inff();
#pragma unroll
  for (int j = 0; j < 8; ++j) {
    float tt = (selv[j] == 0.f) ? NEGV : selv[j];
    selv[j] = tt;
    m8 = fmaxf(m8, tt);
  }
  float Z8 = 0.f;
#pragma unroll
  for (int j = 0; j < 8; ++j) {
    selv[j] = expf(selv[j] - m8);
    Z8 += selv[j];
  }
#pragma unroll
  for (int j = 0; j < 8; ++j) wout[j] = selv[j] / Z8;
}

// ---- user embedding: 4 waves/block, wave = one batch element ----
__global__ __launch_bounds__(256) void k_user(const int* __restrict__ ui,
                                              const float* __restrict__ emb,
                                              const int* __restrict__ clicked,
                                              const float* __restrict__ numc, int hist,
                                              float* __restrict__ user_emb, int ntask) {
  int w = threadIdx.x >> 6, lane = threadIdx.x & 63;
  int b = blockIdx.x * 4 + w;
  if (b >= ntask) return;
  int u = ui[b];
  float acc = 0.f;
  for (int h = 0; h < hist; ++h) {
    int it = clicked[u * hist + h];
    acc += emb[((size_t)it << 6) + lane];
  }
  user_emb[((size_t)b << 6) + lane] = acc * (1.0f / numc[u]);
}

// ---- hop0: score + topsel + transform the 8 selected -> e1, s0w, emb1 ----
__global__ __launch_bounds__(NTHR, 4) void k_hop0_f(
    const int* __restrict__ ii, const float* __restrict__ emb,
    const float* __restrict__ W, const int* __restrict__ adjE,
    const int* __restrict__ adjR, const float* __restrict__ user_emb,
    int* __restrict__ e1, float* __restrict__ s0w, float* __restrict__ emb1,
    int ntask) {
  __shared__ LdsW S;
  stage_W(S.w, W);
  int w = threadIdx.x >> 6, lane = threadIdx.x & 63;
  int wid = blockIdx.x * WPB + w;
  int tot = gridDim.x * WPB;
  for (int t = wid; t < ntask; t += tot) {
    int eid = ii[t];
    int nbr, rel, seli[8];
    float w8[8];
    score_select(eid, t, lane, emb, S.w, adjE, adjR, user_emb, nbr, rel, seli, w8);
#pragma unroll
    for (int j = 0; j < 8; ++j) {
      int sj = __builtin_amdgcn_readfirstlane(seli[j]);
      int nb = __builtin_amdgcn_readlane(nbr, sj);
      int rr = __builtin_amdgcn_readlane(rel, sj);
      float y = transform_rl(nb, rr, lane, emb, S.w);
      emb1[(((size_t)t * 8 + j) << 6) + lane] = y;
      if (lane == 0) {
        e1[t * 8 + j] = nb;
        s0w[t * 8 + j] = w8[j];
      }
    }
  }
}

// ---- hop1: score + topsel + fused aggregation (emb + labels) ----
__global__ __launch_bounds__(NTHR, 4) void k_hop1_f(
    const int* __restrict__ ui, const int* __restrict__ ii, const float* __restrict__ emb,
    const float* __restrict__ W, const int* __restrict__ adjE,
    const int* __restrict__ adjR, const float* __restrict__ labels, int np1,
    const float* __restrict__ user_emb, const int* __restrict__ e1,
    const float* __restrict__ emb1, float* __restrict__ emb1p,
    float* __restrict__ lab1p, int ntask) {
  __shared__ LdsW S;
  stage_W(S.w, W);
  int w = threadIdx.x >> 6, lane = threadIdx.x & 63;
  int wid = blockIdx.x * WPB + w;
  int tot = gridDim.x * WPB;
  for (int bj = wid; bj < ntask; bj += tot) {
    int b = bj >> 3;
    int u = ui[b];
    int item = ii[b];
    int eid = e1[bj];
    int nbr, rel, seli[8];
    float w8[8];
    score_select(eid, b, lane, emb, S.w, adjE, adjR, user_emb, nbr, rel, seli, w8);
    float agg = 0.f, labagg = 0.f;
#pragma unroll
    for (int k = 0; k < 8; ++k) {
      int sk = __builtin_amdgcn_readfirstlane(seli[k]);
      int nb = __builtin_amdgcn_readlane(nbr, sk);
      int rr = __builtin_amdgcn_readlane(rel, sk);
      float wk = w8[k];
      float y = transform_rl(nb, rr, lane, emb, S.w);
      agg = fmaf(wk, y, agg);
      float raw2 = labels[(size_t)u * np1 + nb];  // uniform addr -> scalar load
      float lab2 = (nb != item) ? raw2 : 0.5f;
      labagg = fmaf(wk, lab2, labagg);
    }
    float base = emb1[((size_t)bj << 6) + lane];
    emb1p[((size_t)bj << 6) + lane] = fmaxf(fmaf(agg, 0.125f, base), 0.f);
    if (lane == 0) {
      float raw1 = labels[(size_t)u * np1 + eid];
      bool hm = (eid != item);
      float l1 = hm ? raw1 : 0.5f;
      bool reset1 = (raw1 != 0.5f) && hm;
      lab1p[bj] = reset1 ? l1 : labagg;
    }
  }
}

__global__ __launch_bounds__(256) void k_final(const int* __restrict__ ii,
                                               const float* __restrict__ emb,
                                               const float* __restrict__ user_emb,
                                               const float* __restrict__ s0,
                                               const float* __restrict__ emb1,
                                               const float* __restrict__ emb1p,
                                               const float* __restrict__ lab1p,
                                               float* __restrict__ out, int bs) {
  int w = threadIdx.x >> 6, lane = threadIdx.x & 63;
  int b = blockIdx.x * 4 + w;
  if (b >= bs) return;
  int item = ii[b];
  float ue = user_emb[((size_t)b << 6) + lane];
  float agg = 0.f, aggp = 0.f, lab = 0.f;
#pragma unroll
  for (int j = 0; j < 8; ++j) {
    float s = s0[b * 8 + j];
    agg = fmaf(s, emb1[(((size_t)b * 8 + j) << 6) + lane], agg);
    aggp = fmaf(s, emb1p[(((size_t)b * 8 + j) << 6) + lane], aggp);
    lab = fmaf(s, lab1p[b * 8 + j], lab);
  }
  float e0 = emb[((size_t)item << 6) + lane];
  float h = fmaxf(fmaf(agg, 0.125f, e0), 0.f);  // relu(agg01 + emb0)
  float h2 = tanhf(fmaf(aggp, 0.125f, h));      // tanh(agg01' + emb0')
  float dot = wave_sum(ue * h2);
  if (lane == 0) {
    out[b] = 1.f / (1.f + expf(-dot));
    out[bs + b] = 1.f / (1.f + expf(-(lab - 0.5f)));
  }
}

extern "C" void kernel_launch(void* const* d_in, const int* in_sizes, int n_in, void* d_out,
                              int out_size, void* d_ws, size_t ws_size, hipStream_t stream) {
  const int* ui = (const int*)d_in[0];
  const int* ii = (const int*)d_in[1];
  const float* emb = (const float*)d_in[2];
  const float* W = (const float*)d_in[3];
  const int* adjE = (const int*)d_in[4];
  const int* adjR = (const int*)d_in[5];
  const int* clicked = (const int*)d_in[6];
  const float* numc = (const float*)d_in[7];
  const float* labels = (const float*)d_in[8];

  int bs = in_sizes[0];
  int np1 = in_sizes[2] / 64;  // n_entity + 1 (= labels row stride = offset)
  int nuser = in_sizes[7];
  int hist = in_sizes[6] / nuser;

  // workspace layout
  float* user_emb = (float*)d_ws;               // bs*64
  float* s0w = user_emb + (size_t)bs * 64;      // bs*8
  int* e1 = (int*)(s0w + (size_t)bs * 8);       // bs*8
  float* emb1 = (float*)(e1 + (size_t)bs * 8);  // bs*8*64
  float* emb1p = emb1 + (size_t)bs * 8 * 64;    // bs*8*64
  float* lab1p = emb1p + (size_t)bs * 8 * 64;   // bs*8

  int nt0 = bs;      // hop0 tasks
  int nt1 = bs * 8;  // hop1 tasks
  int nblk0 = (nt0 + WPB - 1) / WPB;  // 1 task per wave

  k_user<<<(nt0 + 3) / 4, 256, 0, stream>>>(ui, emb, clicked, numc, hist, user_emb, nt0);
  k_hop0_f<<<nblk0, NTHR, 0, stream>>>(ii, emb, W, adjE, adjR, user_emb, e1, s0w, emb1,
                                       nt0);
  k_hop1_f<<<256, NTHR, 0, stream>>>(ui, ii, emb, W, adjE, adjR, labels, np1, user_emb,
                                     e1, emb1, emb1p, lab1p, nt1);
  k_final<<<(nt0 + 3) / 4, 256, 0, stream>>>(ii, emb, user_emb, s0w, emb1, emb1p, lab1p,
                                             (float*)d_out, bs);
}

// Round 8
// 282.874 us; speedup vs baseline: 1.3064x; 1.1927x over previous
//
#include <hip/hip_runtime.h>
#include <math.h>

#define NEGV -9000000000000000.0f
#define WPB 16  // waves per block
#define NTHR 1024

// Packed W in LDS: WL[r][k][e] (float4) = W[r][e][4k..4k+3].
// Lane e reads WL[(r*16+k)*64+e]: 64 lanes stride 16B contiguous ->
// conflict-free ds_read_b128. xb = per-wave x staging for broadcast reads.
struct LdsW {
  float4 w[8 * 16 * 64];  // 128 KB
  float xb[WPB][64];      // 4 KB
};

__device__ __forceinline__ float wave_sum(float v) {
#pragma unroll
  for (int m = 32; m; m >>= 1) v += __shfl_xor(v, m, 64);
  return v;
}

// Broadcast lane l's value of v to all lanes via v_readlane (VALU, no DS).
__device__ __forceinline__ float lane_bcast(float v, int l) {
  return __uint_as_float(__builtin_amdgcn_readlane(__float_as_uint(v), l));
}

__device__ __forceinline__ void stage_W(float4* wl, const float* __restrict__ W) {
  const float4* Wg = (const float4*)W;
  for (int f = threadIdx.x; f < 8192; f += NTHR) {
    float4 v = Wg[f];  // coalesced global
    int r = f >> 10, e = (f >> 4) & 63, k = f & 15;
    wl[(((r << 4) + k) << 6) + e] = v;
  }
  __syncthreads();
}

// y = tanh(sum_d W[r][lane][d] * x[d]) with x lane-strided + readlane
// broadcast; W row from LDS. Used only for the 8 selected transforms/task.
__device__ __forceinline__ float transform_rl(int nb, int r, int lane,
                                              const float* __restrict__ emb,
                                              const float4* wl) {
  float xv = emb[((size_t)nb << 6) + lane];  // one lane-strided 256B load
  const float4* wr = wl + (r << 10) + lane;
  float acc = 0.f;
#pragma unroll
  for (int k = 0; k < 16; ++k) {
    float4 w = wr[k << 6];
    acc = fmaf(w.x, lane_bcast(xv, 4 * k + 0), acc);
    acc = fmaf(w.y, lane_bcast(xv, 4 * k + 1), acc);
    acc = fmaf(w.z, lane_bcast(xv, 4 * k + 2), acc);
    acc = fmaf(w.w, lane_bcast(xv, 4 * k + 3), acc);
  }
  return tanhf(acc);
}

// Score 64 neighbors of eid: relation-grouped walk, W of the current relation
// pinned in VGPRs; x broadcast split across DS (d 0..31 via LDS) and VALU
// (d 32..63 via readlane); 1-ahead x prefetch. Masked softmax, top-8
// (value desc, index asc), second masked softmax. All float ops bit-identical
// to prior rounds (same values, same d-ascending fmaf chain).
__device__ __forceinline__ void score_select(int eid, int b, int lane,
                                             const float* __restrict__ emb,
                                             const float4* wl, float* xbuf,
                                             const int* __restrict__ adjE,
                                             const int* __restrict__ adjR,
                                             const float* __restrict__ user_emb,
                                             int& nbr, int& rel, int seli[8],
                                             float wout[8]) {
  nbr = adjE[((size_t)eid << 6) + lane];
  rel = adjR[((size_t)eid << 6) + lane];
  float u_e = user_emb[((size_t)b << 6) + lane];
  // rank of this lane in relation-sorted order (stable within relation)
  int myrank = 0, basec = 0;
  unsigned long long ltmask = (1ull << lane) - 1ull;
#pragma unroll
  for (int rr = 0; rr < 8; ++rr) {
    unsigned long long m = __ballot(rel == rr);
    if (rel == rr) myrank = basec + (int)__popcll(m & ltmask);
    basec += (int)__popcll(m);
  }
  // order[k] = original neighbor index of k-th sorted element (push-permute)
  int order = __builtin_amdgcn_ds_permute(myrank << 2, lane);
  int srt_nb = __shfl(nbr, order, 64);  // neighbor entity of k-th sorted
  int srt_r = __shfl(rel, order, 64);   // relation of k-th sorted

  int nb0 = __builtin_amdgcn_readlane(srt_nb, 0);
  float xv = emb[((size_t)nb0 << 6) + lane];  // prefetch first x
  float4 wv[16];
  int rcur = -1;
  float s_mine = 0.f;
  for (int pos = 0; pos < 64; ++pos) {
    int r = __builtin_amdgcn_readlane(srt_r, pos);
    if (r != rcur) {  // wave-uniform branch; ~7-8 reloads per task
      const float4* wr = wl + (r << 10) + lane;
#pragma unroll
      for (int k = 0; k < 16; ++k) wv[k] = wr[k << 6];
      // pin the W row into VGPRs so the loads can't be sunk into the loop
#pragma unroll
      for (int k = 0; k < 16; ++k)
        asm volatile("" : "+v"(wv[k].x), "+v"(wv[k].y), "+v"(wv[k].z), "+v"(wv[k].w));
      rcur = r;
    }
    float xnext = 0.f;
    if (pos < 63) {  // issue next x load; latency hidden by this matvec
      int nbn = __builtin_amdgcn_readlane(srt_nb, pos + 1);
      xnext = emb[((size_t)nbn << 6) + lane];
    }
    // stage xv for the DS-broadcast half (wave-local ordering)
    __builtin_amdgcn_wave_barrier();
    xbuf[lane] = xv;
    __builtin_amdgcn_wave_barrier();
    asm volatile("s_waitcnt lgkmcnt(0)" ::: "memory");
    __builtin_amdgcn_wave_barrier();
    float acc = 0.f;
#pragma unroll
    for (int k = 0; k < 8; ++k) {  // d 0..31 via LDS broadcast reads
      float4 x = *(const float4*)(xbuf + 4 * k);
      acc = fmaf(wv[k].x, x.x, acc);
      acc = fmaf(wv[k].y, x.y, acc);
      acc = fmaf(wv[k].z, x.z, acc);
      acc = fmaf(wv[k].w, x.w, acc);
    }
#pragma unroll
    for (int k = 8; k < 16; ++k) {  // d 32..63 via readlane (VALU)
      acc = fmaf(wv[k].x, lane_bcast(xv, 4 * k + 0), acc);
      acc = fmaf(wv[k].y, lane_bcast(xv, 4 * k + 1), acc);
      acc = fmaf(wv[k].z, lane_bcast(xv, 4 * k + 2), acc);
      acc = fmaf(wv[k].w, lane_bcast(xv, 4 * k + 3), acc);
    }
    float y = tanhf(acc);
    float totv = wave_sum(u_e * y);
    int n = __builtin_amdgcn_readlane(order, pos);
    if (lane == n) s_mine = totv * (1.0f / 64.0f);
    xv = xnext;
  }
  // ---- masked softmax over 64 neighbors (bit-exact) ----
  float sv = (s_mine == 0.0f) ? NEGV : s_mine;
  float mx = sv;
#pragma unroll
  for (int m = 32; m; m >>= 1) mx = fmaxf(mx, __shfl_xor(mx, m, 64));
  float p = expf(sv - mx);
  float Z = wave_sum(p);
  p /= Z;
  // top-8: iterative butterfly argmax with (value desc, index asc)
  float v = p;
  int vi = lane;
  float selv[8];
#pragma unroll
  for (int j = 0; j < 8; ++j) {
    float bv = v;
    int bi = vi;
#pragma unroll
    for (int m = 1; m < 64; m <<= 1) {
      float ov = __shfl_xor(bv, m, 64);
      int oi = __shfl_xor(bi, m, 64);
      if (ov > bv || (ov == bv && oi < bi)) { bv = ov; bi = oi; }
    }
    selv[j] = bv;
    seli[j] = bi;
    if (lane == bi) v = -__builtin_inff();
  }
  // second masked softmax over the 8 selected
  float m8 = -__builtin_inff();
#pragma unroll
  for (int j = 0; j < 8; ++j) {
    float tt = (selv[j] == 0.f) ? NEGV : selv[j];
    selv[j] = tt;
    m8 = fmaxf(m8, tt);
  }
  float Z8 = 0.f;
#pragma unroll
  for (int j = 0; j < 8; ++j) {
    selv[j] = expf(selv[j] - m8);
    Z8 += selv[j];
  }
#pragma unroll
  for (int j = 0; j < 8; ++j) wout[j] = selv[j] / Z8;
}

// ---- user embedding: 4 waves/block, wave = one batch element ----
__global__ __launch_bounds__(256) void k_user(const int* __restrict__ ui,
                                              const float* __restrict__ emb,
                                              const int* __restrict__ clicked,
                                              const float* __restrict__ numc, int hist,
                                              float* __restrict__ user_emb, int ntask) {
  int w = threadIdx.x >> 6, lane = threadIdx.x & 63;
  int b = blockIdx.x * 4 + w;
  if (b >= ntask) return;
  int u = ui[b];
  float acc = 0.f;
  for (int h = 0; h < hist; ++h) {
    int it = clicked[u * hist + h];
    acc += emb[((size_t)it << 6) + lane];
  }
  user_emb[((size_t)b << 6) + lane] = acc * (1.0f / numc[u]);
}

// ---- hop0: score + topsel + transform the 8 selected -> e1, s0w, emb1 ----
__global__ __launch_bounds__(NTHR, 4) void k_hop0_f(
    const int* __restrict__ ii, const float* __restrict__ emb,
    const float* __restrict__ W, const int* __restrict__ adjE,
    const int* __restrict__ adjR, const float* __restrict__ user_emb,
    int* __restrict__ e1, float* __restrict__ s0w, float* __restrict__ emb1,
    int ntask) {
  __shared__ LdsW S;
  stage_W(S.w, W);
  int w = threadIdx.x >> 6, lane = threadIdx.x & 63;
  int wid = blockIdx.x * WPB + w;
  int tot = gridDim.x * WPB;
  for (int t = wid; t < ntask; t += tot) {
    int eid = ii[t];
    int nbr, rel, seli[8];
    float w8[8];
    score_select(eid, t, lane, emb, S.w, S.xb[w], adjE, adjR, user_emb, nbr, rel, seli,
                 w8);
#pragma unroll
    for (int j = 0; j < 8; ++j) {
      int sj = __builtin_amdgcn_readfirstlane(seli[j]);
      int nb = __builtin_amdgcn_readlane(nbr, sj);
      int rr = __builtin_amdgcn_readlane(rel, sj);
      float y = transform_rl(nb, rr, lane, emb, S.w);
      emb1[(((size_t)t * 8 + j) << 6) + lane] = y;
      if (lane == 0) {
        e1[t * 8 + j] = nb;
        s0w[t * 8 + j] = w8[j];
      }
    }
  }
}

// ---- hop1: score + topsel + fused aggregation (emb + labels) ----
__global__ __launch_bounds__(NTHR, 4) void k_hop1_f(
    const int* __restrict__ ui, const int* __restrict__ ii, const float* __restrict__ emb,
    const float* __restrict__ W, const int* __restrict__ adjE,
    const int* __restrict__ adjR, const float* __restrict__ labels, int np1,
    const float* __restrict__ user_emb, const int* __restrict__ e1,
    const float* __restrict__ emb1, float* __restrict__ emb1p,
    float* __restrict__ lab1p, int ntask) {
  __shared__ LdsW S;
  stage_W(S.w, W);
  int w = threadIdx.x >> 6, lane = threadIdx.x & 63;
  int wid = blockIdx.x * WPB + w;
  int tot = gridDim.x * WPB;
  for (int bj = wid; bj < ntask; bj += tot) {
    int b = bj >> 3;
    int u = ui[b];
    int item = ii[b];
    int eid = e1[bj];
    int nbr, rel, seli[8];
    float w8[8];
    score_select(eid, b, lane, emb, S.w, S.xb[w], adjE, adjR, user_emb, nbr, rel, seli,
                 w8);
    float agg = 0.f, labagg = 0.f;
#pragma unroll
    for (int k = 0; k < 8; ++k) {
      int sk = __builtin_amdgcn_readfirstlane(seli[k]);
      int nb = __builtin_amdgcn_readlane(nbr, sk);
      int rr = __builtin_amdgcn_readlane(rel, sk);
      float wk = w8[k];
      float y = transform_rl(nb, rr, lane, emb, S.w);
      agg = fmaf(wk, y, agg);
      float raw2 = labels[(size_t)u * np1 + nb];  // uniform addr -> scalar load
      float lab2 = (nb != item) ? raw2 : 0.5f;
      labagg = fmaf(wk, lab2, labagg);
    }
    float base = emb1[((size_t)bj << 6) + lane];
    emb1p[((size_t)bj << 6) + lane] = fmaxf(fmaf(agg, 0.125f, base), 0.f);
    if (lane == 0) {
      float raw1 = labels[(size_t)u * np1 + eid];
      bool hm = (eid != item);
      float l1 = hm ? raw1 : 0.5f;
      bool reset1 = (raw1 != 0.5f) && hm;
      lab1p[bj] = reset1 ? l1 : labagg;
    }
  }
}

__global__ __launch_bounds__(256) void k_final(const int* __restrict__ ii,
                                               const float* __restrict__ emb,
                                               const float* __restrict__ user_emb,
                                               const float* __restrict__ s0,
                                               const float* __restrict__ emb1,
                                               const float* __restrict__ emb1p,
                                               const float* __restrict__ lab1p,
                                               float* __restrict__ out, int bs) {
  int w = threadIdx.x >> 6, lane = threadIdx.x & 63;
  int b = blockIdx.x * 4 + w;
  if (b >= bs) return;
  int item = ii[b];
  float ue = user_emb[((size_t)b << 6) + lane];
  float agg = 0.f, aggp = 0.f, lab = 0.f;
#pragma unroll
  for (int j = 0; j < 8; ++j) {
    float s = s0[b * 8 + j];
    agg = fmaf(s, emb1[(((size_t)b * 8 + j) << 6) + lane], agg);
    aggp = fmaf(s, emb1p[(((size_t)b * 8 + j) << 6) + lane], aggp);
    lab = fmaf(s, lab1p[b * 8 + j], lab);
  }
  float e0 = emb[((size_t)item << 6) + lane];
  float h = fmaxf(fmaf(agg, 0.125f, e0), 0.f);  // relu(agg01 + emb0)
  float h2 = tanhf(fmaf(aggp, 0.125f, h));      // tanh(agg01' + emb0')
  float dot = wave_sum(ue * h2);
  if (lane == 0) {
    out[b] = 1.f / (1.f + expf(-dot));
    out[bs + b] = 1.f / (1.f + expf(-(lab - 0.5f)));
  }
}

extern "C" void kernel_launch(void* const* d_in, const int* in_sizes, int n_in, void* d_out,
                              int out_size, void* d_ws, size_t ws_size, hipStream_t stream) {
  const int* ui = (const int*)d_in[0];
  const int* ii = (const int*)d_in[1];
  const float* emb = (const float*)d_in[2];
  const float* W = (const float*)d_in[3];
  const int* adjE = (const int*)d_in[4];
  const int* adjR = (const int*)d_in[5];
  const int* clicked = (const int*)d_in[6];
  const float* numc = (const float*)d_in[7];
  const float* labels = (const float*)d_in[8];

  int bs = in_sizes[0];
  int np1 = in_sizes[2] / 64;  // n_entity + 1 (= labels row stride = offset)
  int nuser = in_sizes[7];
  int hist = in_sizes[6] / nuser;

  // workspace layout
  float* user_emb = (float*)d_ws;               // bs*64
  float* s0w = user_emb + (size_t)bs * 64;      // bs*8
  int* e1 = (int*)(s0w + (size_t)bs * 8);       // bs*8
  float* emb1 = (float*)(e1 + (size_t)bs * 8);  // bs*8*64
  float* emb1p = emb1 + (size_t)bs * 8 * 64;    // bs*8*64
  float* lab1p = emb1p + (size_t)bs * 8 * 64;   // bs*8

  int nt0 = bs;      // hop0 tasks
  int nt1 = bs * 8;  // hop1 tasks
  int nblk0 = (nt0 + WPB - 1) / WPB;  // 1 task per wave

  k_user<<<(nt0 + 3) / 4, 256, 0, stream>>>(ui, emb, clicked, numc, hist, user_emb, nt0);
  k_hop0_f<<<nblk0, NTHR, 0, stream>>>(ii, emb, W, adjE, adjR, user_emb, e1, s0w, emb1,
                                       nt0);
  k_hop1_f<<<256, NTHR, 0, stream>>>(ui, ii, emb, W, adjE, adjR, labels, np1, user_emb,
                                     e1, emb1, emb1p, lab1p, nt1);
  k_final<<<(nt0 + 3) / 4, 256, 0, stream>>>(ii, emb, user_emb, s0w, emb1, emb1p, lab1p,
                                             (float*)d_out, bs);
}

// Round 9
// 282.597 us; speedup vs baseline: 1.3076x; 1.0010x over previous
//
#include <hip/hip_runtime.h>
#include <math.h>

#define NEGV -9000000000000000.0f
#define WPB 16  // waves per block
#define NTHR 1024

// Packed W in LDS: WL[r][k][e] (float4) = W[r][e][4k..4k+3].
// Lane e reads WL[(r*16+k)*64+e]: 64 lanes stride 16B contiguous ->
// conflict-free ds_read_b128. xb = per-wave x staging for broadcast reads.
struct LdsW {
  float4 w[8 * 16 * 64];  // 128 KB
  float xb[WPB][64];      // 4 KB
};

__device__ __forceinline__ float wave_sum(float v) {
#pragma unroll
  for (int m = 32; m; m >>= 1) v += __shfl_xor(v, m, 64);
  return v;
}

// Broadcast lane l's value of v to all lanes via v_readlane (VALU, no DS).
__device__ __forceinline__ float lane_bcast(float v, int l) {
  return __uint_as_float(__builtin_amdgcn_readlane(__float_as_uint(v), l));
}

__device__ __forceinline__ void stage_W(float4* wl, const float* __restrict__ W) {
  const float4* Wg = (const float4*)W;
  for (int f = threadIdx.x; f < 8192; f += NTHR) {
    float4 v = Wg[f];  // coalesced global
    int r = f >> 10, e = (f >> 4) & 63, k = f & 15;
    wl[(((r << 4) + k) << 6) + e] = v;
  }
  __syncthreads();
}

// y = tanh(sum_d W[r][lane][d] * x[d]) with x lane-strided + readlane
// broadcast; W row from LDS. Used only for the 8 selected transforms/task.
__device__ __forceinline__ float transform_rl(int nb, int r, int lane,
                                              const float* __restrict__ emb,
                                              const float4* wl) {
  float xv = emb[((size_t)nb << 6) + lane];  // one lane-strided 256B load
  const float4* wr = wl + (r << 10) + lane;
  float acc = 0.f;
#pragma unroll
  for (int k = 0; k < 16; ++k) {
    float4 w = wr[k << 6];
    acc = fmaf(w.x, lane_bcast(xv, 4 * k + 0), acc);
    acc = fmaf(w.y, lane_bcast(xv, 4 * k + 1), acc);
    acc = fmaf(w.z, lane_bcast(xv, 4 * k + 2), acc);
    acc = fmaf(w.w, lane_bcast(xv, 4 * k + 3), acc);
  }
  return tanhf(acc);
}

// Score 64 neighbors of eid: relation-grouped walk, W of the current relation
// pinned in VGPRs; x broadcast split across DS (d 0..31 via LDS) and VALU
// (d 32..63 via readlane); 1-ahead x prefetch. Masked softmax, top-8
// (value desc, index asc), second masked softmax. All float ops bit-identical
// to prior rounds (same values, same d-ascending fmaf chain).
__device__ __forceinline__ void score_select(int eid, int b, int lane,
                                             const float* __restrict__ emb,
                                             const float4* wl, float* xbuf,
                                             const int* __restrict__ adjE,
                                             const int* __restrict__ adjR,
                                             const float* __restrict__ user_emb,
                                             int& nbr, int& rel, int seli[8],
                                             float wout[8]) {
  nbr = adjE[((size_t)eid << 6) + lane];
  rel = adjR[((size_t)eid << 6) + lane];
  float u_e = user_emb[((size_t)b << 6) + lane];
  // rank of this lane in relation-sorted order (stable within relation)
  int myrank = 0, basec = 0;
  unsigned long long ltmask = (1ull << lane) - 1ull;
#pragma unroll
  for (int rr = 0; rr < 8; ++rr) {
    unsigned long long m = __ballot(rel == rr);
    if (rel == rr) myrank = basec + (int)__popcll(m & ltmask);
    basec += (int)__popcll(m);
  }
  // order[k] = original neighbor index of k-th sorted element (push-permute)
  int order = __builtin_amdgcn_ds_permute(myrank << 2, lane);
  int srt_nb = __shfl(nbr, order, 64);  // neighbor entity of k-th sorted
  int srt_r = __shfl(rel, order, 64);   // relation of k-th sorted

  int nb0 = __builtin_amdgcn_readlane(srt_nb, 0);
  float xv = emb[((size_t)nb0 << 6) + lane];  // prefetch first x
  float4 wv[16];
  int rcur = -1;
  float s_mine = 0.f;
  for (int pos = 0; pos < 64; ++pos) {
    int r = __builtin_amdgcn_readlane(srt_r, pos);
    if (r != rcur) {  // wave-uniform branch; ~7-8 reloads per task
      const float4* wr = wl + (r << 10) + lane;
#pragma unroll
      for (int k = 0; k < 16; ++k) wv[k] = wr[k << 6];
      // pin the W row into VGPRs so the loads can't be sunk into the loop
#pragma unroll
      for (int k = 0; k < 16; ++k)
        asm volatile("" : "+v"(wv[k].x), "+v"(wv[k].y), "+v"(wv[k].z), "+v"(wv[k].w));
      rcur = r;
    }
    float xnext = 0.f;
    if (pos < 63) {  // issue next x load; latency hidden by this matvec
      int nbn = __builtin_amdgcn_readlane(srt_nb, pos + 1);
      xnext = emb[((size_t)nbn << 6) + lane];
    }
    // stage xv for the DS-broadcast half (wave-local ordering)
    __builtin_amdgcn_wave_barrier();
    xbuf[lane] = xv;
    __builtin_amdgcn_wave_barrier();
    asm volatile("s_waitcnt lgkmcnt(0)" ::: "memory");
    __builtin_amdgcn_wave_barrier();
    float acc = 0.f;
#pragma unroll
    for (int k = 0; k < 8; ++k) {  // d 0..31 via LDS broadcast reads
      float4 x = *(const float4*)(xbuf + 4 * k);
      acc = fmaf(wv[k].x, x.x, acc);
      acc = fmaf(wv[k].y, x.y, acc);
      acc = fmaf(wv[k].z, x.z, acc);
      acc = fmaf(wv[k].w, x.w, acc);
    }
#pragma unroll
    for (int k = 8; k < 16; ++k) {  // d 32..63 via readlane (VALU)
      acc = fmaf(wv[k].x, lane_bcast(xv, 4 * k + 0), acc);
      acc = fmaf(wv[k].y, lane_bcast(xv, 4 * k + 1), acc);
      acc = fmaf(wv[k].z, lane_bcast(xv, 4 * k + 2), acc);
      acc = fmaf(wv[k].w, lane_bcast(xv, 4 * k + 3), acc);
    }
    float y = tanhf(acc);
    float totv = wave_sum(u_e * y);
    int n = __builtin_amdgcn_readlane(order, pos);
    if (lane == n) s_mine = totv * (1.0f / 64.0f);
    xv = xnext;
  }
  // ---- masked softmax over 64 neighbors (bit-exact) ----
  float sv = (s_mine == 0.0f) ? NEGV : s_mine;
  float mx = sv;
#pragma unroll
  for (int m = 32; m; m >>= 1) mx = fmaxf(mx, __shfl_xor(mx, m, 64));
  float p = expf(sv - mx);
  float Z = wave_sum(p);
  p /= Z;
  // top-8: iterative butterfly argmax with (value desc, index asc)
  float v = p;
  int vi = lane;
  float selv[8];
#pragma unroll
  for (int j = 0; j < 8; ++j) {
    float bv = v;
    int bi = vi;
#pragma unroll
    for (int m = 1; m < 64; m <<= 1) {
      float ov = __shfl_xor(bv, m, 64);
      int oi = __shfl_xor(bi, m, 64);
      if (ov > bv || (ov == bv && oi < bi)) { bv = ov; bi = oi; }
    }
    selv[j] = bv;
    seli[j] = bi;
    if (lane == bi) v = -__builtin_inff();
  }
  // second masked softmax over the 8 selected
  float m8 = -__builtin_inff();
#pragma unroll
  for (int j = 0; j < 8; ++j) {
    float tt = (selv[j] == 0.f) ? NEGV : selv[j];
    selv[j] = tt;
    m8 = fmaxf(m8, tt);
  }
  float Z8 = 0.f;
#pragma unroll
  for (int j = 0; j < 8; ++j) {
    selv[j] = expf(selv[j] - m8);
    Z8 += selv[j];
  }
#pragma unroll
  for (int j = 0; j < 8; ++j) wout[j] = selv[j] / Z8;
}

// ---- user embedding: 4 waves/block, wave = one batch element ----
__global__ __launch_bounds__(256) void k_user(const int* __restrict__ ui,
                                              const float* __restrict__ emb,
                                              const int* __restrict__ clicked,
                                              const float* __restrict__ numc, int hist,
                                              float* __restrict__ user_emb, int ntask) {
  int w = threadIdx.x >> 6, lane = threadIdx.x & 63;
  int b = blockIdx.x * 4 + w;
  if (b >= ntask) return;
  int u = ui[b];
  float acc = 0.f;
  for (int h = 0; h < hist; ++h) {
    int it = clicked[u * hist + h];
    acc += emb[((size_t)it << 6) + lane];
  }
  user_emb[((size_t)b << 6) + lane] = acc * (1.0f / numc[u]);
}

// ---- hop0: score + topsel + transform the 8 selected -> e1, s0w, emb1 ----
__global__ __launch_bounds__(NTHR, 4) void k_hop0_f(
    const int* __restrict__ ii, const float* __restrict__ emb,
    const float* __restrict__ W, const int* __restrict__ adjE,
    const int* __restrict__ adjR, const float* __restrict__ user_emb,
    int* __restrict__ e1, float* __restrict__ s0w, float* __restrict__ emb1,
    int ntask) {
  __shared__ LdsW S;
  stage_W(S.w, W);
  int w = threadIdx.x >> 6, lane = threadIdx.x & 63;
  int wid = blockIdx.x * WPB + w;
  int tot = gridDim.x * WPB;
  for (int t = wid; t < ntask; t += tot) {
    int eid = ii[t];
    int nbr, rel, seli[8];
    float w8[8];
    score_select(eid, t, lane, emb, S.w, S.xb[w], adjE, adjR, user_emb, nbr, rel, seli,
                 w8);
#pragma unroll
    for (int j = 0; j < 8; ++j) {
      int sj = __builtin_amdgcn_readfirstlane(seli[j]);
      int nb = __builtin_amdgcn_readlane(nbr, sj);
      int rr = __builtin_amdgcn_readlane(rel, sj);
      float y = transform_rl(nb, rr, lane, emb, S.w);
      emb1[(((size_t)t * 8 + j) << 6) + lane] = y;
      if (lane == 0) {
        e1[t * 8 + j] = nb;
        s0w[t * 8 + j] = w8[j];
      }
    }
  }
}

// ---- hop1: score + topsel + fused aggregation (emb + labels) ----
__global__ __launch_bounds__(NTHR, 4) void k_hop1_f(
    const int* __restrict__ ui, const int* __restrict__ ii, const float* __restrict__ emb,
    const float* __restrict__ W, const int* __restrict__ adjE,
    const int* __restrict__ adjR, const float* __restrict__ labels, int np1,
    const float* __restrict__ user_emb, const int* __restrict__ e1,
    const float* __restrict__ emb1, float* __restrict__ emb1p,
    float* __restrict__ lab1p, int ntask) {
  __shared__ LdsW S;
  stage_W(S.w, W);
  int w = threadIdx.x >> 6, lane = threadIdx.x & 63;
  int wid = blockIdx.x * WPB + w;
  int tot = gridDim.x * WPB;
  for (int bj = wid; bj < ntask; bj += tot) {
    int b = bj >> 3;
    int u = ui[b];
    int item = ii[b];
    int eid = e1[bj];
    int nbr, rel, seli[8];
    float w8[8];
    score_select(eid, b, lane, emb, S.w, S.xb[w], adjE, adjR, user_emb, nbr, rel, seli,
                 w8);
    float agg = 0.f, labagg = 0.f;
#pragma unroll
    for (int k = 0; k < 8; ++k) {
      int sk = __builtin_amdgcn_readfirstlane(seli[k]);
      int nb = __builtin_amdgcn_readlane(nbr, sk);
      int rr = __builtin_amdgcn_readlane(rel, sk);
      float wk = w8[k];
      float y = transform_rl(nb, rr, lane, emb, S.w);
      agg = fmaf(wk, y, agg);
      float raw2 = labels[(size_t)u * np1 + nb];  // uniform addr -> scalar load
      float lab2 = (nb != item) ? raw2 : 0.5f;
      labagg = fmaf(wk, lab2, labagg);
    }
    float base = emb1[((size_t)bj << 6) + lane];
    emb1p[((size_t)bj << 6) + lane] = fmaxf(fmaf(agg, 0.125f, base), 0.f);
    if (lane == 0) {
      float raw1 = labels[(size_t)u * np1 + eid];
      bool hm = (eid != item);
      float l1 = hm ? raw1 : 0.5f;
      bool reset1 = (raw1 != 0.5f) && hm;
      lab1p[bj] = reset1 ? l1 : labagg;
    }
  }
}

__global__ __launch_bounds__(256) void k_final(const int* __restrict__ ii,
                                               const float* __restrict__ emb,
                                               const float* __restrict__ user_emb,
                                               const float* __restrict__ s0,
                                               const float* __restrict__ emb1,
                                               const float* __restrict__ emb1p,
                                               const float* __restrict__ lab1p,
                                               float* __restrict__ out, int bs) {
  int w = threadIdx.x >> 6, lane = threadIdx.x & 63;
  int b = blockIdx.x * 4 + w;
  if (b >= bs) return;
  int item = ii[b];
  float ue = user_emb[((size_t)b << 6) + lane];
  float agg = 0.f, aggp = 0.f, lab = 0.f;
#pragma unroll
  for (int j = 0; j < 8; ++j) {
    float s = s0[b * 8 + j];
    agg = fmaf(s, emb1[(((size_t)b * 8 + j) << 6) + lane], agg);
    aggp = fmaf(s, emb1p[(((size_t)b * 8 + j) << 6) + lane], aggp);
    lab = fmaf(s, lab1p[b * 8 + j], lab);
  }
  float e0 = emb[((size_t)item << 6) + lane];
  float h = fmaxf(fmaf(agg, 0.125f, e0), 0.f);  // relu(agg01 + emb0)
  float h2 = tanhf(fmaf(aggp, 0.125f, h));      // tanh(agg01' + emb0')
  float dot = wave_sum(ue * h2);
  if (lane == 0) {
    out[b] = 1.f / (1.f + expf(-dot));
    out[bs + b] = 1.f / (1.f + expf(-(lab - 0.5f)));
  }
}

extern "C" void kernel_launch(void* const* d_in, const int* in_sizes, int n_in, void* d_out,
                              int out_size, void* d_ws, size_t ws_size, hipStream_t stream) {
  const int* ui = (const int*)d_in[0];
  const int* ii = (const int*)d_in[1];
  const float* emb = (const float*)d_in[2];
  const float* W = (const float*)d_in[3];
  const int* adjE = (const int*)d_in[4];
  const int* adjR = (const int*)d_in[5];
  const int* clicked = (const int*)d_in[6];
  const float* numc = (const float*)d_in[7];
  const float* labels = (const float*)d_in[8];

  int bs = in_sizes[0];
  int np1 = in_sizes[2] / 64;  // n_entity + 1 (= labels row stride = offset)
  int nuser = in_sizes[7];
  int hist = in_sizes[6] / nuser;

  // workspace layout
  float* user_emb = (float*)d_ws;               // bs*64
  float* s0w = user_emb + (size_t)bs * 64;      // bs*8
  int* e1 = (int*)(s0w + (size_t)bs * 8);       // bs*8
  float* emb1 = (float*)(e1 + (size_t)bs * 8);  // bs*8*64
  float* emb1p = emb1 + (size_t)bs * 8 * 64;    // bs*8*64
  float* lab1p = emb1p + (size_t)bs * 8 * 64;   // bs*8

  int nt0 = bs;      // hop0 tasks
  int nt1 = bs * 8;  // hop1 tasks
  int nblk0 = (nt0 + WPB - 1) / WPB;  // 1 task per wave

  k_user<<<(nt0 + 3) / 4, 256, 0, stream>>>(ui, emb, clicked, numc, hist, user_emb, nt0);
  k_hop0_f<<<nblk0, NTHR, 0, stream>>>(ii, emb, W, adjE, adjR, user_emb, e1, s0w, emb1,
                                       nt0);
  k_hop1_f<<<256, NTHR, 0, stream>>>(ui, ii, emb, W, adjE, adjR, labels, np1, user_emb,
                                     e1, emb1, emb1p, lab1p, nt1);
  k_final<<<(nt0 + 3) / 4, 256, 0, stream>>>(ii, emb, user_emb, s0w, emb1, emb1p, lab1p,
                                             (float*)d_out, bs);
}

// Round 10
// 229.892 us; speedup vs baseline: 1.6074x; 1.2293x over previous
//
#include <hip/hip_runtime.h>
#include <math.h>

#define NEGV -9000000000000000.0f
#define WPB 16  // waves per block
#define NTHR 1024

// Packed W in LDS: WL[r][k][e] (float4) = W[r][e][4k..4k+3].
// Lane e reads WL[(r*16+k)*64+e]: 64 lanes stride 16B contiguous ->
// conflict-free ds_read_b128. xb = per-wave x staging for broadcast reads.
struct LdsW {
  float4 w[8 * 16 * 64];  // 128 KB
  float xb[WPB][64];      // 4 KB
};

__device__ __forceinline__ float wave_sum(float v) {
#pragma unroll
  for (int m = 32; m; m >>= 1) v += __shfl_xor(v, m, 64);
  return v;
}

__device__ __forceinline__ void stage_W(float4* wl, const float* __restrict__ W) {
  const float4* Wg = (const float4*)W;
  for (int f = threadIdx.x; f < 8192; f += NTHR) {
    float4 v = Wg[f];  // coalesced global
    int r = f >> 10, e = (f >> 4) & 63, k = f & 15;
    wl[(((r << 4) + k) << 6) + e] = v;
  }
  __syncthreads();
}

// y = tanh(sum_d W[r][lane][d] * x[d]); x fully via wave-uniform loads
// (nb is an SGPR value -> s_load, values broadcast as SGPR fma operands).
// fmaf chain order (d ascending) identical to all prior rounds -> bit-exact.
__device__ __forceinline__ float transform_su(int nb, int r, int lane,
                                              const float* __restrict__ emb,
                                              const float4* wl) {
  const float4* xg = (const float4*)(emb + ((size_t)nb << 6));
  float4 xu[16];
#pragma unroll
  for (int k = 0; k < 16; ++k) xu[k] = xg[k];  // uniform -> scalar loads
  const float4* wr = wl + (r << 10) + lane;
  float acc = 0.f;
#pragma unroll
  for (int k = 0; k < 16; ++k) {
    float4 w = wr[k << 6];
    acc = fmaf(w.x, xu[k].x, acc);
    acc = fmaf(w.y, xu[k].y, acc);
    acc = fmaf(w.z, xu[k].z, acc);
    acc = fmaf(w.w, xu[k].w, acc);
  }
  return tanhf(acc);
}

// Score 64 neighbors of eid: relation-grouped walk, W of the current relation
// pinned in VGPRs; x broadcast split: d0..31 via per-wave LDS staging
// (broadcast ds_read_b128), d32..63 via wave-uniform SMEM loads (SGPR fma
// operands, issued before the lgkm fence so latency hides under staging).
// 1-ahead prefetch of the lane-strided x row. Masked softmax, top-8
// (value desc, index asc), second masked softmax. All float ops bit-identical
// to prior rounds (same values, same d-ascending fmaf chain).
__device__ __forceinline__ void score_select(int eid, int b, int lane,
                                             const float* __restrict__ emb,
                                             const float4* wl, float* xbuf,
                                             const int* __restrict__ adjE,
                                             const int* __restrict__ adjR,
                                             const float* __restrict__ user_emb,
                                             int& nbr, int& rel, int seli[8],
                                             float wout[8]) {
  nbr = adjE[((size_t)eid << 6) + lane];
  rel = adjR[((size_t)eid << 6) + lane];
  float u_e = user_emb[((size_t)b << 6) + lane];
  // rank of this lane in relation-sorted order (stable within relation)
  int myrank = 0, basec = 0;
  unsigned long long ltmask = (1ull << lane) - 1ull;
#pragma unroll
  for (int rr = 0; rr < 8; ++rr) {
    unsigned long long m = __ballot(rel == rr);
    if (rel == rr) myrank = basec + (int)__popcll(m & ltmask);
    basec += (int)__popcll(m);
  }
  // order[k] = original neighbor index of k-th sorted element (push-permute)
  int order = __builtin_amdgcn_ds_permute(myrank << 2, lane);
  int srt_nb = __shfl(nbr, order, 64);  // neighbor entity of k-th sorted
  int srt_r = __shfl(rel, order, 64);   // relation of k-th sorted

  int nb0 = __builtin_amdgcn_readlane(srt_nb, 0);
  float xv = emb[((size_t)nb0 << 6) + lane];  // prefetch first x row
  float4 wv[16];
  int rcur = -1;
  float s_mine = 0.f;
  for (int pos = 0; pos < 64; ++pos) {
    int r = __builtin_amdgcn_readlane(srt_r, pos);
    if (r != rcur) {  // wave-uniform branch; ~7-8 reloads per task
      const float4* wr = wl + (r << 10) + lane;
#pragma unroll
      for (int k = 0; k < 16; ++k) wv[k] = wr[k << 6];
      // pin the W row into VGPRs so the loads can't be sunk into the loop
#pragma unroll
      for (int k = 0; k < 16; ++k)
        asm volatile("" : "+v"(wv[k].x), "+v"(wv[k].y), "+v"(wv[k].z), "+v"(wv[k].w));
      rcur = r;
    }
    // upper half d32..63 via uniform loads (SGPRs); issued before the fence
    int nbc = __builtin_amdgcn_readlane(srt_nb, pos);
    const float4* xg = (const float4*)(emb + ((size_t)nbc << 6) + 32);
    float4 xu[8];
#pragma unroll
    for (int j = 0; j < 8; ++j) xu[j] = xg[j];
    float xnext = 0.f;
    if (pos < 63) {  // issue next x row load; latency hidden by this matvec
      int nbn = __builtin_amdgcn_readlane(srt_nb, pos + 1);
      xnext = emb[((size_t)nbn << 6) + lane];
    }
    // stage xv for the DS-broadcast half (wave-local ordering)
    __builtin_amdgcn_wave_barrier();
    xbuf[lane] = xv;
    __builtin_amdgcn_wave_barrier();
    asm volatile("s_waitcnt lgkmcnt(0)" ::: "memory");  // waits write + s_loads
    __builtin_amdgcn_wave_barrier();
    float acc = 0.f;
#pragma unroll
    for (int k = 0; k < 8; ++k) {  // d 0..31 via LDS broadcast reads
      float4 x = *(const float4*)(xbuf + 4 * k);
      acc = fmaf(wv[k].x, x.x, acc);
      acc = fmaf(wv[k].y, x.y, acc);
      acc = fmaf(wv[k].z, x.z, acc);
      acc = fmaf(wv[k].w, x.w, acc);
    }
#pragma unroll
    for (int k = 8; k < 16; ++k) {  // d 32..63 via SGPR operands
      acc = fmaf(wv[k].x, xu[k - 8].x, acc);
      acc = fmaf(wv[k].y, xu[k - 8].y, acc);
      acc = fmaf(wv[k].z, xu[k - 8].z, acc);
      acc = fmaf(wv[k].w, xu[k - 8].w, acc);
    }
    float y = tanhf(acc);
    float totv = wave_sum(u_e * y);
    int n = __builtin_amdgcn_readlane(order, pos);
    if (lane == n) s_mine = totv * (1.0f / 64.0f);
    xv = xnext;
  }
  // ---- masked softmax over 64 neighbors (bit-exact) ----
  float sv = (s_mine == 0.0f) ? NEGV : s_mine;
  float mx = sv;
#pragma unroll
  for (int m = 32; m; m >>= 1) mx = fmaxf(mx, __shfl_xor(mx, m, 64));
  float p = expf(sv - mx);
  float Z = wave_sum(p);
  p /= Z;
  // top-8: iterative butterfly argmax with (value desc, index asc)
  float v = p;
  int vi = lane;
  float selv[8];
#pragma unroll
  for (int j = 0; j < 8; ++j) {
    float bv = v;
    int bi = vi;
#pragma unroll
    for (int m = 1; m < 64; m <<= 1) {
      float ov = __shfl_xor(bv, m, 64);
      int oi = __shfl_xor(bi, m, 64);
      if (ov > bv || (ov == bv && oi < bi)) { bv = ov; bi = oi; }
    }
    selv[j] = bv;
    seli[j] = bi;
    if (lane == bi) v = -__builtin_inff();
  }
  // second masked softmax over the 8 selected
  float m8 = -__builtin_inff();
#pragma unroll
  for (int j = 0; j < 8; ++j) {
    float tt = (selv[j] == 0.f) ? NEGV : selv[j];
    selv[j] = tt;
    m8 = fmaxf(m8, tt);
  }
  float Z8 = 0.f;
#pragma unroll
  for (int j = 0; j < 8; ++j) {
    selv[j] = expf(selv[j] - m8);
    Z8 += selv[j];
  }
#pragma unroll
  for (int j = 0; j < 8; ++j) wout[j] = selv[j] / Z8;
}

// ---- user embedding: 4 waves/block, wave = one batch element ----
__global__ __launch_bounds__(256) void k_user(const int* __restrict__ ui,
                                              const float* __restrict__ emb,
                                              const int* __restrict__ clicked,
                                              const float* __restrict__ numc, int hist,
                                              float* __restrict__ user_emb, int ntask) {
  int w = threadIdx.x >> 6, lane = threadIdx.x & 63;
  int b = blockIdx.x * 4 + w;
  if (b >= ntask) return;
  int u = ui[b];
  float acc = 0.f;
  for (int h = 0; h < hist; ++h) {
    int it = clicked[u * hist + h];
    acc += emb[((size_t)it << 6) + lane];
  }
  user_emb[((size_t)b << 6) + lane] = acc * (1.0f / numc[u]);
}

// ---- hop0: score + topsel + transform the 8 selected -> e1, s0w, emb1 ----
__global__ __launch_bounds__(NTHR, 4) void k_hop0_f(
    const int* __restrict__ ii, const float* __restrict__ emb,
    const float* __restrict__ W, const int* __restrict__ adjE,
    const int* __restrict__ adjR, const float* __restrict__ user_emb,
    int* __restrict__ e1, float* __restrict__ s0w, float* __restrict__ emb1,
    int ntask) {
  __shared__ LdsW S;
  stage_W(S.w, W);
  int w = threadIdx.x >> 6, lane = threadIdx.x & 63;
  int wid = blockIdx.x * WPB + w;
  int tot = gridDim.x * WPB;
  for (int t = wid; t < ntask; t += tot) {
    int eid = ii[t];
    int nbr, rel, seli[8];
    float w8[8];
    score_select(eid, t, lane, emb, S.w, S.xb[w], adjE, adjR, user_emb, nbr, rel, seli,
                 w8);
#pragma unroll
    for (int j = 0; j < 8; ++j) {
      int sj = __builtin_amdgcn_readfirstlane(seli[j]);
      int nb = __builtin_amdgcn_readlane(nbr, sj);
      int rr = __builtin_amdgcn_readlane(rel, sj);
      float y = transform_su(nb, rr, lane, emb, S.w);
      emb1[(((size_t)t * 8 + j) << 6) + lane] = y;
      if (lane == 0) {
        e1[t * 8 + j] = nb;
        s0w[t * 8 + j] = w8[j];
      }
    }
  }
}

// ---- hop1: score + topsel + fused aggregation (emb + labels) ----
__global__ __launch_bounds__(NTHR, 4) void k_hop1_f(
    const int* __restrict__ ui, const int* __restrict__ ii, const float* __restrict__ emb,
    const float* __restrict__ W, const int* __restrict__ adjE,
    const int* __restrict__ adjR, const float* __restrict__ labels, int np1,
    const float* __restrict__ user_emb, const int* __restrict__ e1,
    const float* __restrict__ emb1, float* __restrict__ emb1p,
    float* __restrict__ lab1p, int ntask) {
  __shared__ LdsW S;
  stage_W(S.w, W);
  int w = threadIdx.x >> 6, lane = threadIdx.x & 63;
  int wid = blockIdx.x * WPB + w;
  int tot = gridDim.x * WPB;
  for (int bj = wid; bj < ntask; bj += tot) {
    int b = bj >> 3;
    int u = ui[b];
    int item = ii[b];
    int eid = e1[bj];
    int nbr, rel, seli[8];
    float w8[8];
    score_select(eid, b, lane, emb, S.w, S.xb[w], adjE, adjR, user_emb, nbr, rel, seli,
                 w8);
    float agg = 0.f, labagg = 0.f;
#pragma unroll
    for (int k = 0; k < 8; ++k) {
      int sk = __builtin_amdgcn_readfirstlane(seli[k]);
      int nb = __builtin_amdgcn_readlane(nbr, sk);
      int rr = __builtin_amdgcn_readlane(rel, sk);
      float wk = w8[k];
      float y = transform_su(nb, rr, lane, emb, S.w);
      agg = fmaf(wk, y, agg);
      float raw2 = labels[(size_t)u * np1 + nb];  // uniform addr -> scalar load
      float lab2 = (nb != item) ? raw2 : 0.5f;
      labagg = fmaf(wk, lab2, labagg);
    }
    float base = emb1[((size_t)bj << 6) + lane];
    emb1p[((size_t)bj << 6) + lane] = fmaxf(fmaf(agg, 0.125f, base), 0.f);
    if (lane == 0) {
      float raw1 = labels[(size_t)u * np1 + eid];
      bool hm = (eid != item);
      float l1 = hm ? raw1 : 0.5f;
      bool reset1 = (raw1 != 0.5f) && hm;
      lab1p[bj] = reset1 ? l1 : labagg;
    }
  }
}

__global__ __launch_bounds__(256) void k_final(const int* __restrict__ ii,
                                               const float* __restrict__ emb,
                                               const float* __restrict__ user_emb,
                                               const float* __restrict__ s0,
                                               const float* __restrict__ emb1,
                                               const float* __restrict__ emb1p,
                                               const float* __restrict__ lab1p,
                                               float* __restrict__ out, int bs) {
  int w = threadIdx.x >> 6, lane = threadIdx.x & 63;
  int b = blockIdx.x * 4 + w;
  if (b >= bs) return;
  int item = ii[b];
  float ue = user_emb[((size_t)b << 6) + lane];
  float agg = 0.f, aggp = 0.f, lab = 0.f;
#pragma unroll
  for (int j = 0; j < 8; ++j) {
    float s = s0[b * 8 + j];
    agg = fmaf(s, emb1[(((size_t)b * 8 + j) << 6) + lane], agg);
    aggp = fmaf(s, emb1p[(((size_t)b * 8 + j) << 6) + lane], aggp);
    lab = fmaf(s, lab1p[b * 8 + j], lab);
  }
  float e0 = emb[((size_t)item << 6) + lane];
  float h = fmaxf(fmaf(agg, 0.125f, e0), 0.f);  // relu(agg01 + emb0)
  float h2 = tanhf(fmaf(aggp, 0.125f, h));      // tanh(agg01' + emb0')
  float dot = wave_sum(ue * h2);
  if (lane == 0) {
    out[b] = 1.f / (1.f + expf(-dot));
    out[bs + b] = 1.f / (1.f + expf(-(lab - 0.5f)));
  }
}

extern "C" void kernel_launch(void* const* d_in, const int* in_sizes, int n_in, void* d_out,
                              int out_size, void* d_ws, size_t ws_size, hipStream_t stream) {
  const int* ui = (const int*)d_in[0];
  const int* ii = (const int*)d_in[1];
  const float* emb = (const float*)d_in[2];
  const float* W = (const float*)d_in[3];
  const int* adjE = (const int*)d_in[4];
  const int* adjR = (const int*)d_in[5];
  const int* clicked = (const int*)d_in[6];
  const float* numc = (const float*)d_in[7];
  const float* labels = (const float*)d_in[8];

  int bs = in_sizes[0];
  int np1 = in_sizes[2] / 64;  // n_entity + 1 (= labels row stride = offset)
  int nuser = in_sizes[7];
  int hist = in_sizes[6] / nuser;

  // workspace layout
  float* user_emb = (float*)d_ws;               // bs*64
  float* s0w = user_emb + (size_t)bs * 64;      // bs*8
  int* e1 = (int*)(s0w + (size_t)bs * 8);       // bs*8
  float* emb1 = (float*)(e1 + (size_t)bs * 8);  // bs*8*64
  float* emb1p = emb1 + (size_t)bs * 8 * 64;    // bs*8*64
  float* lab1p = emb1p + (size_t)bs * 8 * 64;   // bs*8

  int nt0 = bs;      // hop0 tasks
  int nt1 = bs * 8;  // hop1 tasks

  k_user<<<(nt0 + 3) / 4, 256, 0, stream>>>(ui, emb, clicked, numc, hist, user_emb, nt0);
  // hop0 on the FULL machine (grid-stride handles ntask < nwaves)
  k_hop0_f<<<256, NTHR, 0, stream>>>(ii, emb, W, adjE, adjR, user_emb, e1, s0w, emb1,
                                     nt0);
  k_hop1_f<<<256, NTHR, 0, stream>>>(ui, ii, emb, W, adjE, adjR, labels, np1, user_emb,
                                     e1, emb1, emb1p, lab1p, nt1);
  k_final<<<(nt0 + 3) / 4, 256, 0, stream>>>(ii, emb, user_emb, s0w, emb1, emb1p, lab1p,
                                             (float*)d_out, bs);
}